// Round 18
// baseline (357.611 us; speedup 1.0000x reference)
//
#include <hip/hip_runtime.h>
#include <hip/hip_bf16.h>

#define NTOK 8192   // B*T tokens
#define DDIM 1024
#define FDIM 2048
#define NEXP 16
#define CAP   1280  // max token slots per expert (cnt ~1024 expected)
#define CAPRG 80    // CAP/16 row-groups

// ---------------- workspace layout (bytes) ----------------
#define WS_COUNTS 0                                  // int[16*16], 64B-padded per expert
#define WS_TOKL   4096
#define WS_WGTL   (4096 + NTOK*NEXP*4)
#define WS_POS    (4096 + 2*NTOK*NEXP*4)            // int[NTOK*2]
#define WS_TW     (4096 + 2*NTOK*NEXP*4 + NTOK*8)   // float[NTOK*2]
#define WS2_XG   (size_t)(2u<<20)     // 40 MB: Xg (g1 input), then reused as Yp (g2 out)
#define WS2_W1   (size_t)(42u<<20)    // 64 MB: 16*128*32 chunks  (std frag order)
#define WS2_W2   (size_t)(106u<<20)   // 64 MB: 16*64*64 chunks   (SIGMA frag order)
#define WS2_UG   (size_t)(170u<<20)   // 80 MB: 16*80*64 chunks   (SIGMA frag order)

typedef short bf16x8 __attribute__((ext_vector_type(8)));
typedef float f32x4  __attribute__((ext_vector_type(4)));

__device__ __forceinline__ unsigned short f2bf(float f) {
  unsigned int u = __builtin_bit_cast(unsigned int, f);
  u += 0x7fffu + ((u >> 16) & 1u);            // RNE
  return (unsigned short)(u >> 16);
}
__device__ __forceinline__ unsigned int pk2(float a, float b) {
  return (unsigned int)f2bf(a) | ((unsigned int)f2bf(b) << 16);
}
__device__ __forceinline__ float bf2f(unsigned int u) {
  return __builtin_bit_cast(float, u << 16);
}
__device__ __forceinline__ float silu_f(float s) {
  return s / (1.f + __expf(-s));
}
__device__ __forceinline__ void gld_lds16(const void* g, void* l) {
  __builtin_amdgcn_global_load_lds((const __attribute__((address_space(1))) void*)g,
                                   (__attribute__((address_space(3))) void*)l, 16, 0, 0);
}

// ---------------- gate v3: block-aggregated slot allocation, padded counters ----------
__global__ __launch_bounds__(1024) void gate_kernel(
    const float* __restrict__ x, const float* __restrict__ Wg,
    int* __restrict__ counts, int* __restrict__ tokl, float* __restrict__ wgtl,
    int* __restrict__ pos, float* __restrict__ tw) {
  __shared__ float WgT[NEXP][DDIM];            // 64 KB
  __shared__ int   se[32];
  __shared__ float swt[32];
  __shared__ int   sbase[16];
  int tid = threadIdx.x;
#pragma unroll
  for (int i = 0; i < 4; ++i) {
    int i4 = i * 1024 + tid;
    float4 v = ((const float4*)Wg)[i4];
    int k = i4 >> 2;
    int e0 = (i4 * 4) & 15;
    WgT[e0][k] = v.x; WgT[e0 + 1][k] = v.y;
    WgT[e0 + 2][k] = v.z; WgT[e0 + 3][k] = v.w;
  }
  __syncthreads();

  int wid = tid >> 6, lane = tid & 63;
  int tok = blockIdx.x * 16 + wid;
  const float* xr = x + (size_t)tok * DDIM;
  float xv[16];
#pragma unroll
  for (int j = 0; j < 16; ++j) xv[j] = xr[lane + 64 * j];
  float lg[NEXP];
#pragma unroll
  for (int e = 0; e < NEXP; ++e) {
    float s = 0.f;
#pragma unroll
    for (int j = 0; j < 16; ++j) s += xv[j] * WgT[e][lane + 64 * j];
#pragma unroll
    for (int off = 32; off > 0; off >>= 1) s += __shfl_xor(s, off);
    lg[e] = s;
  }
  int e0 = 0; float b0 = lg[0];
#pragma unroll
  for (int e = 1; e < NEXP; ++e) if (lg[e] > b0) { b0 = lg[e]; e0 = e; }
  int e1 = -1; float b1 = -3.4e38f;
#pragma unroll
  for (int e = 0; e < NEXP; ++e) if (e != e0 && lg[e] > b1) { b1 = lg[e]; e1 = e; }
  float t = expf(b1 - b0);
  float w0 = 1.f / (1.f + t);
  float w1 = t / (1.f + t);
  if (lane == 0) {
    se[wid * 2] = e0;  swt[wid * 2] = w0;
    se[wid * 2 + 1] = e1;  swt[wid * 2 + 1] = w1;
  }
  __syncthreads();

  if (tid < 16) {
    int cnt = 0;
#pragma unroll
    for (int i = 0; i < 32; ++i) cnt += (se[i] == tid) ? 1 : 0;
    sbase[tid] = cnt ? atomicAdd(&counts[tid * 16], cnt) : 0;
    int slot = sbase[tid];
    for (int i = 0; i < 32; ++i) {
      if (se[i] == tid) {
        int tk = blockIdx.x * 16 + (i >> 1);
        float w = swt[i];
        if (slot < CAP) { tokl[tid * NTOK + slot] = tk; wgtl[tid * NTOK + slot] = w; }
        pos[tk * 2 + (i & 1)] = (slot < CAP) ? (tid * CAP + slot) : -1;
        tw[tk * 2 + (i & 1)] = w;
        slot++;
      }
    }
  }
}

// ---------------- W fp32 -> bf16 frag-ordered, LDS-transposed (coalesced reads) ----
__global__ __launch_bounds__(256) void convert_w2(
    const float* __restrict__ W1, const float* __restrict__ W2,
    unsigned short* __restrict__ W1s, unsigned short* __restrict__ W2s) {
  __shared__ float tile[32][133];
  int b = blockIdx.x;
  bool isw2 = b >= 8192;
  int bb = isw2 ? b - 8192 : b;
  int e = bb >> 9;
  int r = bb & 511;
  int t = threadIdx.x;
  const float* src;
  int kk, cb, C;
  if (!isw2) {
    kk = r >> 4; cb = r & 15; C = FDIM;
    src = W1 + ((size_t)e << 21) + (size_t)(kk * 32) * FDIM + cb * 128;
  } else {
    kk = r >> 3; cb = r & 7; C = DDIM;
    src = W2 + ((size_t)e << 21) + (size_t)(kk * 32) * DDIM + cb * 128;
  }
  int c4 = (t & 31) * 4, rr0 = t >> 5;
#pragma unroll
  for (int rd = 0; rd < 4; ++rd) {
    int rr = rr0 + rd * 8;
    float4 v = *(const float4*)(src + (size_t)rr * C + c4);
    tile[rr][c4] = v.x; tile[rr][c4 + 1] = v.y;
    tile[rr][c4 + 2] = v.z; tile[rr][c4 + 3] = v.w;
  }
  __syncthreads();
  int w = t >> 6, lane = t & 63, llo = lane & 15, lhi = lane >> 4;
#pragma unroll
  for (int u = 0; u < 2; ++u) {
    int c2 = w * 2 + u;
    float v[8];
#pragma unroll
    for (int j = 0; j < 8; ++j) {
      int row = isw2 ? (4 * lhi + (j & 3) + 16 * (j >> 2)) : (lhi * 8 + j);
      v[j] = tile[row][c2 * 16 + llo];
    }
    uint4 o;
    o.x = pk2(v[0], v[1]); o.y = pk2(v[2], v[3]);
    o.z = pk2(v[4], v[5]); o.w = pk2(v[6], v[7]);
    size_t gid = isw2 ? (((size_t)e * 64 + kk) * 64 + (cb * 8 + c2))
                      : (((size_t)e * 128 + (cb * 8 + c2)) * 32 + kk);
    *(uint4*)((isw2 ? W2s : W1s) + (gid << 9) + lane * 8) = o;
  }
}

// ---------------- gather x -> Xg frag-ordered bf16, zero-padded slots ----------------
__global__ __launch_bounds__(512) void gather_x(
    const float* __restrict__ x, const int* __restrict__ counts,
    const int* __restrict__ tokl, unsigned short* __restrict__ Xg) {
  int chunk = blockIdx.x * 8 + (threadIdx.x >> 6);   // 40960 chunks
  int lane = threadIdx.x & 63, llo = lane & 15, lhi = lane >> 4;
  int kb = chunk & 31;
  int rg = (chunk >> 5) % CAPRG;
  int e = chunk / (CAPRG * 32);
  int cnt = min(counts[e * 16], CAP);
  int slot = rg * 16 + llo;
  uint4 o = {0u, 0u, 0u, 0u};
  if (slot < cnt) {
    int tok = tokl[e * NTOK + slot];
    const float* p = x + (size_t)tok * DDIM + kb * 32 + lhi * 8;
    float4 a = *(const float4*)p, b2 = *(const float4*)(p + 4);
    o.x = pk2(a.x, a.y); o.y = pk2(a.z, a.w);
    o.z = pk2(b2.x, b2.y); o.w = pk2(b2.z, b2.w);
  }
  *(uint4*)(Xg + ((size_t)chunk << 9) + lane * 8) = o;
}

// ======== G1: U = silu(X @ W1e), 128f x 128tok, BK=32, 4-buffer depth-3 pipeline ====
// 64 KB LDS (4 x 16KB) -> 2 blocks/CU. Per wave: 2 staged chunks/tile.
// Ledger: end of step t retire tile t+1 -> vmcnt(2*[(t+2<NT)] + 2*[(t+3<NT)]).
__global__ __launch_bounds__(512, 4) void g1(
    const unsigned short* __restrict__ W1s, const unsigned short* __restrict__ Xg,
    const int* __restrict__ counts, unsigned short* __restrict__ Ug) {
  int id = blockIdx.x;
  int e = ((id & 7) << 1) | ((id >> 3) & 1);
  int rest = id >> 4;          // 0..159
  int ft = rest & 15;          // f-tile (128 f)
  int tt = rest >> 4;          // tok-tile (128 slots), 0..9
  int cnt = min(counts[e * 16], CAP);
  if (tt * 128 >= cnt) return;

  extern __shared__ char smem[];                 // 4 x (A 8KB | B 8KB)
  int tid = threadIdx.x, wid = tid >> 6, lane = tid & 63;
  int llo = lane & 15, lhi = lane >> 4;
  int fm = wid >> 2, wn = wid & 3;               // wave = f-half(2) x tok-quarter(4)

  f32x4 acc[4][2];                               // per wave: 64 f x 32 tok
#pragma unroll
  for (int i = 0; i < 4; ++i)
#pragma unroll
    for (int j = 0; j < 2; ++j) acc[i][j] = (f32x4){0.f, 0.f, 0.f, 0.f};

  const size_t abase = ((size_t)e * 128 + ft * 8) * 32;      // W1s chunk base (8 ff)
  const size_t bbase = ((size_t)e * CAPRG + tt * 8) * 32;    // Xg chunk base (8 rg)

  // per-wave staging pointers (2 chunks), stride 512 shorts (1 chunk) per tile
  const int c0 = wid * 2;
  const unsigned short* gsrc0;
  const unsigned short* gsrc1;
  {
    int c = c0;
    gsrc0 = (c < 8) ? W1s + ((abase + (size_t)c * 32) << 9) + lane * 8
                    : Xg + ((bbase + (size_t)(c - 8) * 32) << 9) + lane * 8;
    c = c0 + 1;
    gsrc1 = (c < 8) ? W1s + ((abase + (size_t)c * 32) << 9) + lane * 8
                    : Xg + ((bbase + (size_t)(c - 8) * 32) << 9) + lane * 8;
  }
  const int doff0 = (c0 + 0) * 1024;
  const int doff1 = (c0 + 1) * 1024;
  const int lo16 = lane * 16;
  const int aoff = fm * 4096;                    // af region base (A = [0,8K))
  const int boff = 8192 + wn * 2048;             // bx region base (B = [8K,16K))

#define G1_STAGE(ROT)                                                           \
  {                                                                             \
    char* dst = smem + (ROT);                                                   \
    gld_lds16(gsrc0, dst + doff0);                                              \
    gld_lds16(gsrc1, dst + doff1);                                              \
    gsrc0 += 512; gsrc1 += 512;                                                 \
  }

  G1_STAGE(0);
  G1_STAGE(16384);
  G1_STAGE(32768);
  asm volatile("s_waitcnt vmcnt(4)" ::: "memory");   // tile 0 landed; 1,2 in flight
  __builtin_amdgcn_s_barrier();
  int rotw = 49152, rotr = 0;
  for (int t = 0; t < 32; ++t) {                 // K = 1024, BK = 32
    if (t + 3 < 32) G1_STAGE(rotw);
    const char* bufc = smem + rotr;
    bf16x8 af[4], bx[2];
#pragma unroll
    for (int fi = 0; fi < 4; ++fi)
      af[fi] = *(const bf16x8*)(bufc + aoff + fi * 1024 + lo16);
#pragma unroll
    for (int ti = 0; ti < 2; ++ti)
      bx[ti] = *(const bf16x8*)(bufc + boff + ti * 1024 + lo16);
#pragma unroll
    for (int fi = 0; fi < 4; ++fi)
#pragma unroll
      for (int ti = 0; ti < 2; ++ti)
        acc[fi][ti] = __builtin_amdgcn_mfma_f32_16x16x32_bf16(af[fi], bx[ti], acc[fi][ti], 0, 0, 0);
    // drain this wave's LDS reads before any wave can overwrite this buffer
    asm volatile("s_waitcnt lgkmcnt(0)" ::: "memory");
    __builtin_amdgcn_sched_barrier(0);
    if (t + 3 < 32) {
      asm volatile("s_waitcnt vmcnt(4)" ::: "memory");   // retire t+1; t+2,t+3 in flight
    } else if (t + 2 < 32) {
      asm volatile("s_waitcnt vmcnt(2)" ::: "memory");   // retire t+1; t+2 in flight
    } else if (t + 1 < 32) {
      asm volatile("s_waitcnt vmcnt(0)" ::: "memory");   // tail: drain t+1
    }
    __builtin_amdgcn_s_barrier();
    rotw = (rotw == 49152) ? 0 : rotw + 16384;
    rotr = (rotr == 49152) ? 0 : rotr + 16384;
  }

  // epilogue: silu -> Ug (SIGMA order), coalesced 16B stores straight from regs
#pragma unroll
  for (int ti = 0; ti < 2; ++ti) {
    int rg = tt * 8 + wn * 2 + ti;
#pragma unroll
    for (int p = 0; p < 2; ++p) {
      int fo = ft * 4 + fm * 2 + p;
      uint4 v;
      v.x = pk2(silu_f(acc[2 * p][ti][0]), silu_f(acc[2 * p][ti][1]));
      v.y = pk2(silu_f(acc[2 * p][ti][2]), silu_f(acc[2 * p][ti][3]));
      v.z = pk2(silu_f(acc[2 * p + 1][ti][0]), silu_f(acc[2 * p + 1][ti][1]));
      v.w = pk2(silu_f(acc[2 * p + 1][ti][2]), silu_f(acc[2 * p + 1][ti][3]));
      *(uint4*)(Ug + ((((size_t)e * CAPRG + rg) * 64 + fo) << 9) + lane * 8) = v;
    }
  }
}

// ======== G2: Yp = U @ W2e, 128d x 128tok, BK=32, 4-buffer depth-3 pipeline ========
__global__ __launch_bounds__(512, 4) void g2(
    const unsigned short* __restrict__ W2s, const unsigned short* __restrict__ Ug,
    const int* __restrict__ counts, unsigned short* __restrict__ Yp) {
  int id = blockIdx.x;
  int e = ((id & 7) << 1) | ((id >> 3) & 1);
  int rest = id >> 4;          // 0..79
  int dt = rest & 7;           // d-tile (128 d)
  int tt = rest >> 3;          // tok-tile (128 slots), 0..9
  int cnt = min(counts[e * 16], CAP);
  int tb0 = tt * 128;
  if (tb0 >= cnt) return;

  extern __shared__ char smem[];
  int tid = threadIdx.x;
  int wid = tid >> 6, lane = tid & 63, llo = lane & 15, lhi = lane >> 4;
  int dm = wid >> 2, wn = wid & 3;               // wave = d-half(2) x tok-quarter(4)

  f32x4 acc[4][2];                               // per wave: 64 d x 32 tok
#pragma unroll
  for (int i = 0; i < 4; ++i)
#pragma unroll
    for (int j = 0; j < 2; ++j) acc[i][j] = (f32x4){0.f, 0.f, 0.f, 0.f};

  const size_t bbase = ((size_t)e * CAPRG + tt * 8) * 64;    // Ug chunk base (8 rg)

  // per-wave staging pointers; stride/tile: W2s +64 chunks (=32768), Ug +1 (=512)
  const int c0 = wid * 2;
  const unsigned short* gsrc0;
  const unsigned short* gsrc1;
  int st01;
  {
    if (c0 < 8) {
      gsrc0 = W2s + ((((size_t)e * 64) * 64 + dt * 8 + c0) << 9) + lane * 8;
      gsrc1 = W2s + ((((size_t)e * 64) * 64 + dt * 8 + c0 + 1) << 9) + lane * 8;
      st01 = 32768;
    } else {
      gsrc0 = Ug + ((bbase + (size_t)(c0 - 8) * 64) << 9) + lane * 8;
      gsrc1 = Ug + ((bbase + (size_t)(c0 - 7) * 64) << 9) + lane * 8;
      st01 = 512;
    }
  }
  const int doff0 = (c0 + 0) * 1024;
  const int doff1 = (c0 + 1) * 1024;
  const int lo16 = lane * 16;
  const int aoff = dm * 4096;
  const int boff = 8192 + wn * 2048;

#define G2_STAGE(ROT)                                                           \
  {                                                                             \
    char* dst = smem + (ROT);                                                   \
    gld_lds16(gsrc0, dst + doff0);                                              \
    gld_lds16(gsrc1, dst + doff1);                                              \
    gsrc0 += st01; gsrc1 += st01;                                               \
  }

  G2_STAGE(0);
  G2_STAGE(16384);
  G2_STAGE(32768);
  asm volatile("s_waitcnt vmcnt(4)" ::: "memory");
  __builtin_amdgcn_s_barrier();
  int rotw = 49152, rotr = 0;
  for (int t = 0; t < 64; ++t) {                 // K = 2048, BK = 32
    if (t + 3 < 64) G2_STAGE(rotw);
    const char* bufc = smem + rotr;
    bf16x8 aw[4], bu[2];
#pragma unroll
    for (int di = 0; di < 4; ++di)
      aw[di] = *(const bf16x8*)(bufc + aoff + di * 1024 + lo16);
#pragma unroll
    for (int ti = 0; ti < 2; ++ti)
      bu[ti] = *(const bf16x8*)(bufc + boff + ti * 1024 + lo16);
#pragma unroll
    for (int di = 0; di < 4; ++di)
#pragma unroll
      for (int ti = 0; ti < 2; ++ti)
        acc[di][ti] = __builtin_amdgcn_mfma_f32_16x16x32_bf16(aw[di], bu[ti], acc[di][ti], 0, 0, 0);
    asm volatile("s_waitcnt lgkmcnt(0)" ::: "memory");
    __builtin_amdgcn_sched_barrier(0);
    if (t + 3 < 64) {
      asm volatile("s_waitcnt vmcnt(4)" ::: "memory");
    } else if (t + 2 < 64) {
      asm volatile("s_waitcnt vmcnt(2)" ::: "memory");
    } else if (t + 1 < 64) {
      asm volatile("s_waitcnt vmcnt(0)" ::: "memory");
    }
    __builtin_amdgcn_s_barrier();
    rotw = (rotw == 49152) ? 0 : rotw + 16384;
    rotr = (rotr == 49152) ? 0 : rotr + 16384;
  }

  // epilogue: plain bf16 partial stores (no RMW, no atomics)
#pragma unroll
  for (int di = 0; di < 4; ++di)
#pragma unroll
    for (int ti = 0; ti < 2; ++ti) {
      int slot = tb0 + wn * 32 + ti * 16 + llo;
      int d = dt * 128 + dm * 64 + di * 16 + 4 * lhi;
      uint2 v;
      v.x = pk2(acc[di][ti][0], acc[di][ti][1]);
      v.y = pk2(acc[di][ti][2], acc[di][ti][3]);
      *(uint2*)(Yp + (((size_t)e * CAP + slot) << 10) + d) = v;
    }
}

// ---------------- combine: out[tok] = w0*Yp[p0] + w1*Yp[p1] (streaming) ----------
__global__ __launch_bounds__(256) void combine_k(
    const unsigned short* __restrict__ Yp, const int* __restrict__ pos,
    const float* __restrict__ tw, float* __restrict__ out) {
  int gid = blockIdx.x * 256 + threadIdx.x;    // 1,048,576 threads
  int tok = gid >> 7, oct = gid & 127;
  int p0 = pos[tok * 2], p1 = pos[tok * 2 + 1];
  float w0 = tw[tok * 2], w1 = tw[tok * 2 + 1];
  float r[8];
#pragma unroll
  for (int j = 0; j < 8; ++j) r[j] = 0.f;
  if (p0 >= 0) {
    uint4 a = *(const uint4*)(Yp + (((size_t)p0) << 10) + (oct << 3));
    unsigned int w[4] = {a.x, a.y, a.z, a.w};
#pragma unroll
    for (int h = 0; h < 4; ++h) {
      r[2 * h]     += w0 * bf2f(w[h] & 0xffffu);
      r[2 * h + 1] += w0 * bf2f(w[h] >> 16);
    }
  }
  if (p1 >= 0) {
    uint4 a = *(const uint4*)(Yp + (((size_t)p1) << 10) + (oct << 3));
    unsigned int w[4] = {a.x, a.y, a.z, a.w};
#pragma unroll
    for (int h = 0; h < 4; ++h) {
      r[2 * h]     += w1 * bf2f(w[h] & 0xffffu);
      r[2 * h + 1] += w1 * bf2f(w[h] >> 16);
    }
  }
  float4 o0 = {r[0], r[1], r[2], r[3]}, o1 = {r[4], r[5], r[6], r[7]};
  float* dst = out + ((size_t)tok << 10) + (oct << 3);
  *(float4*)dst = o0;
  *(float4*)(dst + 4) = o1;
}

extern "C" void kernel_launch(void* const* d_in, const int* in_sizes, int n_in,
                              void* d_out, int out_size, void* d_ws, size_t ws_size,
                              hipStream_t stream) {
  const float* x  = (const float*)d_in[0];
  const float* Wg = (const float*)d_in[1];
  const float* W1 = (const float*)d_in[2];
  const float* W2 = (const float*)d_in[3];
  float* out = (float*)d_out;

  int*   counts = (int*)((char*)d_ws + WS_COUNTS);   // padded: counts[e*16]
  int*   tokl   = (int*)((char*)d_ws + WS_TOKL);
  float* wgtl   = (float*)((char*)d_ws + WS_WGTL);
  int*   pos    = (int*)((char*)d_ws + WS_POS);
  float* tw     = (float*)((char*)d_ws + WS_TW);
  unsigned short* XgN = (unsigned short*)((char*)d_ws + WS2_XG);  // Xg, then Yp
  unsigned short* W1n = (unsigned short*)((char*)d_ws + WS2_W1);
  unsigned short* W2n = (unsigned short*)((char*)d_ws + WS2_W2);
  unsigned short* UgN = (unsigned short*)((char*)d_ws + WS2_UG);

  hipMemsetAsync(counts, 0, 1024, stream);

  gate_kernel<<<NTOK / 16, 1024, 0, stream>>>(x, Wg, counts, tokl, wgtl, pos, tw);
  convert_w2<<<16384, 256, 0, stream>>>(W1, W2, W1n, W2n);
  gather_x<<<5120, 512, 0, stream>>>(x, counts, tokl, XgN);

  hipFuncSetAttribute((const void*)g1,
                      hipFuncAttributeMaxDynamicSharedMemorySize, 65536);
  hipFuncSetAttribute((const void*)g2,
                      hipFuncAttributeMaxDynamicSharedMemorySize, 65536);
  g1<<<NEXP * 16 * 10, 512, 65536, stream>>>(W1n, XgN, counts, UgN);
  g2<<<NEXP * 8 * 10, 512, 65536, stream>>>(W2n, UgN, counts, XgN /* = Yp */);
  combine_k<<<4096, 256, 0, stream>>>(XgN /* = Yp */, pos, tw, out);
}

// Round 19
// 342.361 us; speedup vs baseline: 1.0445x; 1.0445x over previous
//
#include <hip/hip_runtime.h>
#include <hip/hip_bf16.h>

#define NTOK 8192   // B*T tokens
#define DDIM 1024
#define FDIM 2048
#define NEXP 16
#define CAP   1280  // max token slots per expert (cnt ~1024 expected)
#define CAPRG 80    // CAP/16 row-groups

// ---------------- workspace layout (bytes) ----------------
#define WS_COUNTS 0                                  // int[16*16], 64B-padded per expert
#define WS_TOKL   4096
#define WS_WGTL   (4096 + NTOK*NEXP*4)
#define WS_POS    (4096 + 2*NTOK*NEXP*4)            // int[NTOK*2]
#define WS_TW     (4096 + 2*NTOK*NEXP*4 + NTOK*8)   // float[NTOK*2]
#define WS2_XG   (size_t)(2u<<20)     // 40 MB: Xg (g1 input), then reused as Yp (g2 out)
#define WS2_W1   (size_t)(42u<<20)    // 64 MB: 16*128*32 chunks  (std frag order)
#define WS2_W2   (size_t)(106u<<20)   // 64 MB: 16*64*64 chunks   (SIGMA frag order)
#define WS2_UG   (size_t)(170u<<20)   // 80 MB: 16*80*64 chunks   (SIGMA frag order)

typedef short bf16x8 __attribute__((ext_vector_type(8)));
typedef float f32x4  __attribute__((ext_vector_type(4)));

__device__ __forceinline__ unsigned short f2bf(float f) {
  unsigned int u = __builtin_bit_cast(unsigned int, f);
  u += 0x7fffu + ((u >> 16) & 1u);            // RNE
  return (unsigned short)(u >> 16);
}
__device__ __forceinline__ unsigned int pk2(float a, float b) {
  return (unsigned int)f2bf(a) | ((unsigned int)f2bf(b) << 16);
}
__device__ __forceinline__ float bf2f(unsigned int u) {
  return __builtin_bit_cast(float, u << 16);
}
__device__ __forceinline__ float silu_f(float s) {
  return s / (1.f + __expf(-s));
}
__device__ __forceinline__ void gld_lds16(const void* g, void* l) {
  __builtin_amdgcn_global_load_lds((const __attribute__((address_space(1))) void*)g,
                                   (__attribute__((address_space(3))) void*)l, 16, 0, 0);
}

// ---------------- gate v3: block-aggregated slot allocation, padded counters ----------
__global__ __launch_bounds__(1024) void gate_kernel(
    const float* __restrict__ x, const float* __restrict__ Wg,
    int* __restrict__ counts, int* __restrict__ tokl, float* __restrict__ wgtl,
    int* __restrict__ pos, float* __restrict__ tw) {
  __shared__ float WgT[NEXP][DDIM];            // 64 KB
  __shared__ int   se[32];
  __shared__ float swt[32];
  __shared__ int   sbase[16];
  int tid = threadIdx.x;
#pragma unroll
  for (int i = 0; i < 4; ++i) {
    int i4 = i * 1024 + tid;
    float4 v = ((const float4*)Wg)[i4];
    int k = i4 >> 2;
    int e0 = (i4 * 4) & 15;
    WgT[e0][k] = v.x; WgT[e0 + 1][k] = v.y;
    WgT[e0 + 2][k] = v.z; WgT[e0 + 3][k] = v.w;
  }
  __syncthreads();

  int wid = tid >> 6, lane = tid & 63;
  int tok = blockIdx.x * 16 + wid;
  const float* xr = x + (size_t)tok * DDIM;
  float xv[16];
#pragma unroll
  for (int j = 0; j < 16; ++j) xv[j] = xr[lane + 64 * j];
  float lg[NEXP];
#pragma unroll
  for (int e = 0; e < NEXP; ++e) {
    float s = 0.f;
#pragma unroll
    for (int j = 0; j < 16; ++j) s += xv[j] * WgT[e][lane + 64 * j];
#pragma unroll
    for (int off = 32; off > 0; off >>= 1) s += __shfl_xor(s, off);
    lg[e] = s;
  }
  int e0 = 0; float b0 = lg[0];
#pragma unroll
  for (int e = 1; e < NEXP; ++e) if (lg[e] > b0) { b0 = lg[e]; e0 = e; }
  int e1 = -1; float b1 = -3.4e38f;
#pragma unroll
  for (int e = 0; e < NEXP; ++e) if (e != e0 && lg[e] > b1) { b1 = lg[e]; e1 = e; }
  float t = expf(b1 - b0);
  float w0 = 1.f / (1.f + t);
  float w1 = t / (1.f + t);
  if (lane == 0) {
    se[wid * 2] = e0;  swt[wid * 2] = w0;
    se[wid * 2 + 1] = e1;  swt[wid * 2 + 1] = w1;
  }
  __syncthreads();

  if (tid < 16) {
    int cnt = 0;
#pragma unroll
    for (int i = 0; i < 32; ++i) cnt += (se[i] == tid) ? 1 : 0;
    sbase[tid] = cnt ? atomicAdd(&counts[tid * 16], cnt) : 0;
    int slot = sbase[tid];
    for (int i = 0; i < 32; ++i) {
      if (se[i] == tid) {
        int tk = blockIdx.x * 16 + (i >> 1);
        float w = swt[i];
        if (slot < CAP) { tokl[tid * NTOK + slot] = tk; wgtl[tid * NTOK + slot] = w; }
        pos[tk * 2 + (i & 1)] = (slot < CAP) ? (tid * CAP + slot) : -1;
        tw[tk * 2 + (i & 1)] = w;
        slot++;
      }
    }
  }
}

// ---------------- W fp32 -> bf16 frag-ordered, LDS-transposed (coalesced reads) ----
__global__ __launch_bounds__(256) void convert_w2(
    const float* __restrict__ W1, const float* __restrict__ W2,
    unsigned short* __restrict__ W1s, unsigned short* __restrict__ W2s) {
  __shared__ float tile[32][133];
  int b = blockIdx.x;
  bool isw2 = b >= 8192;
  int bb = isw2 ? b - 8192 : b;
  int e = bb >> 9;
  int r = bb & 511;
  int t = threadIdx.x;
  const float* src;
  int kk, cb, C;
  if (!isw2) {
    kk = r >> 4; cb = r & 15; C = FDIM;
    src = W1 + ((size_t)e << 21) + (size_t)(kk * 32) * FDIM + cb * 128;
  } else {
    kk = r >> 3; cb = r & 7; C = DDIM;
    src = W2 + ((size_t)e << 21) + (size_t)(kk * 32) * DDIM + cb * 128;
  }
  int c4 = (t & 31) * 4, rr0 = t >> 5;
#pragma unroll
  for (int rd = 0; rd < 4; ++rd) {
    int rr = rr0 + rd * 8;
    float4 v = *(const float4*)(src + (size_t)rr * C + c4);
    tile[rr][c4] = v.x; tile[rr][c4 + 1] = v.y;
    tile[rr][c4 + 2] = v.z; tile[rr][c4 + 3] = v.w;
  }
  __syncthreads();
  int w = t >> 6, lane = t & 63, llo = lane & 15, lhi = lane >> 4;
#pragma unroll
  for (int u = 0; u < 2; ++u) {
    int c2 = w * 2 + u;
    float v[8];
#pragma unroll
    for (int j = 0; j < 8; ++j) {
      int row = isw2 ? (4 * lhi + (j & 3) + 16 * (j >> 2)) : (lhi * 8 + j);
      v[j] = tile[row][c2 * 16 + llo];
    }
    uint4 o;
    o.x = pk2(v[0], v[1]); o.y = pk2(v[2], v[3]);
    o.z = pk2(v[4], v[5]); o.w = pk2(v[6], v[7]);
    size_t gid = isw2 ? (((size_t)e * 64 + kk) * 64 + (cb * 8 + c2))
                      : (((size_t)e * 128 + (cb * 8 + c2)) * 32 + kk);
    *(uint4*)((isw2 ? W2s : W1s) + (gid << 9) + lane * 8) = o;
  }
}

// ---------------- gather x -> Xg frag-ordered bf16, zero-padded slots ----------------
__global__ __launch_bounds__(512) void gather_x(
    const float* __restrict__ x, const int* __restrict__ counts,
    const int* __restrict__ tokl, unsigned short* __restrict__ Xg) {
  int chunk = blockIdx.x * 8 + (threadIdx.x >> 6);   // 40960 chunks
  int lane = threadIdx.x & 63, llo = lane & 15, lhi = lane >> 4;
  int kb = chunk & 31;
  int rg = (chunk >> 5) % CAPRG;
  int e = chunk / (CAPRG * 32);
  int cnt = min(counts[e * 16], CAP);
  int slot = rg * 16 + llo;
  uint4 o = {0u, 0u, 0u, 0u};
  if (slot < cnt) {
    int tok = tokl[e * NTOK + slot];
    const float* p = x + (size_t)tok * DDIM + kb * 32 + lhi * 8;
    float4 a = *(const float4*)p, b2 = *(const float4*)(p + 4);
    o.x = pk2(a.x, a.y); o.y = pk2(a.z, a.w);
    o.z = pk2(b2.x, b2.y); o.w = pk2(b2.z, b2.w);
  }
  *(uint4*)(Xg + ((size_t)chunk << 9) + lane * 8) = o;
}

// ======== G1: U = silu(X @ W1e), 128f x 256tok, BK=32, 3-buffer depth-2 pipeline ====
// Best-known config (R17): counted vmcnt(3), lgkm fence + sched_barrier before
// each barrier, strength-reduced addressing, 72 KB LDS -> 2 blocks/CU.
__global__ __launch_bounds__(512, 4) void g1(
    const unsigned short* __restrict__ W1s, const unsigned short* __restrict__ Xg,
    const int* __restrict__ counts, unsigned short* __restrict__ Ug) {
  int id = blockIdx.x;
  int e = ((id & 7) << 1) | ((id >> 3) & 1);
  int rest = id >> 4;          // 0..79
  int ft = rest & 15;          // f-tile (128 f)
  int tt = rest >> 4;          // tok-tile (256 slots), 0..4
  int cnt = min(counts[e * 16], CAP);
  if (tt * 256 >= cnt) return;

  extern __shared__ char smem[];                 // 3 x (A 8KB | B 16KB)
  int tid = threadIdx.x, wid = tid >> 6, lane = tid & 63;
  int llo = lane & 15, lhi = lane >> 4;
  int fm = wid >> 2, wn = wid & 3;               // wave = f-half(2) x tok-quarter(4)

  f32x4 acc[4][4];                               // per wave: 64 f x 64 tok
#pragma unroll
  for (int i = 0; i < 4; ++i)
#pragma unroll
    for (int j = 0; j < 4; ++j) acc[i][j] = (f32x4){0.f, 0.f, 0.f, 0.f};

  const size_t abase = ((size_t)e * 128 + ft * 8) * 32;      // W1s chunk base (8 ff)
  const size_t bbase = ((size_t)e * CAPRG + tt * 16) * 32;   // Xg chunk base (16 rg)

  // per-wave staging pointers (3 chunks), stride 512 shorts (1 chunk) per tile
  const int c0 = wid * 3;
  const unsigned short* gsrc0;
  const unsigned short* gsrc1;
  const unsigned short* gsrc2;
  {
    int c = c0;
    gsrc0 = (c < 8) ? W1s + ((abase + (size_t)c * 32) << 9) + lane * 8
                    : Xg + ((bbase + (size_t)(c - 8) * 32) << 9) + lane * 8;
    c = c0 + 1;
    gsrc1 = (c < 8) ? W1s + ((abase + (size_t)c * 32) << 9) + lane * 8
                    : Xg + ((bbase + (size_t)(c - 8) * 32) << 9) + lane * 8;
    c = c0 + 2;
    gsrc2 = (c < 8) ? W1s + ((abase + (size_t)c * 32) << 9) + lane * 8
                    : Xg + ((bbase + (size_t)(c - 8) * 32) << 9) + lane * 8;
  }
  const int doff0 = (c0 + 0) * 1024;
  const int doff1 = (c0 + 1) * 1024;
  const int doff2 = (c0 + 2) * 1024;
  const int lo16 = lane * 16;
  const int aoff = fm * 4096;                    // af region base
  const int boff = 8192 + wn * 4096;             // bx region base

#define G1_STAGE(ROT)                                                           \
  {                                                                             \
    char* dst = smem + (ROT);                                                   \
    gld_lds16(gsrc0, dst + doff0);                                              \
    gld_lds16(gsrc1, dst + doff1);                                              \
    gld_lds16(gsrc2, dst + doff2);                                              \
    gsrc0 += 512; gsrc1 += 512; gsrc2 += 512;                                   \
  }

  G1_STAGE(0);
  G1_STAGE(24576);
  asm volatile("s_waitcnt vmcnt(3)" ::: "memory");
  __builtin_amdgcn_s_barrier();
  int rotw = 49152, rotr = 0;
  for (int t = 0; t < 32; ++t) {                 // K = 1024, BK = 32
    if (t + 2 < 32) G1_STAGE(rotw);
    const char* bufc = smem + rotr;
    bf16x8 af[4], bx[4];
#pragma unroll
    for (int fi = 0; fi < 4; ++fi)
      af[fi] = *(const bf16x8*)(bufc + aoff + fi * 1024 + lo16);
#pragma unroll
    for (int ti = 0; ti < 4; ++ti)
      bx[ti] = *(const bf16x8*)(bufc + boff + ti * 1024 + lo16);
#pragma unroll
    for (int fi = 0; fi < 4; ++fi)
#pragma unroll
      for (int ti = 0; ti < 4; ++ti)
        acc[fi][ti] = __builtin_amdgcn_mfma_f32_16x16x32_bf16(af[fi], bx[ti], acc[fi][ti], 0, 0, 0);
    // drain this wave's LDS reads before any wave can overwrite this buffer
    asm volatile("s_waitcnt lgkmcnt(0)" ::: "memory");
    __builtin_amdgcn_sched_barrier(0);
    if (t + 2 < 32) {
      asm volatile("s_waitcnt vmcnt(3)" ::: "memory");   // retire tile t+1; t+2 in flight
    } else if (t + 1 < 32) {
      asm volatile("s_waitcnt vmcnt(0)" ::: "memory");   // tail: drain t+1
    }
    __builtin_amdgcn_s_barrier();
    rotw = (rotw == 49152) ? 0 : rotw + 24576;
    rotr = (rotr == 49152) ? 0 : rotr + 24576;
  }

  // epilogue: silu -> Ug (SIGMA order), coalesced 16B stores straight from regs
#pragma unroll
  for (int ti = 0; ti < 4; ++ti) {
    int rg = tt * 16 + wn * 4 + ti;
#pragma unroll
    for (int p = 0; p < 2; ++p) {
      int fo = ft * 4 + fm * 2 + p;
      uint4 v;
      v.x = pk2(silu_f(acc[2 * p][ti][0]), silu_f(acc[2 * p][ti][1]));
      v.y = pk2(silu_f(acc[2 * p][ti][2]), silu_f(acc[2 * p][ti][3]));
      v.z = pk2(silu_f(acc[2 * p + 1][ti][0]), silu_f(acc[2 * p + 1][ti][1]));
      v.w = pk2(silu_f(acc[2 * p + 1][ti][2]), silu_f(acc[2 * p + 1][ti][3]));
      *(uint4*)(Ug + ((((size_t)e * CAPRG + rg) * 64 + fo) << 9) + lane * 8) = v;
    }
  }
}

// ======== G2: Yp = U @ W2e, 128d x 256tok, BK=32, 3-buffer depth-2 pipeline ========
__global__ __launch_bounds__(512, 4) void g2(
    const unsigned short* __restrict__ W2s, const unsigned short* __restrict__ Ug,
    const int* __restrict__ counts, unsigned short* __restrict__ Yp) {
  int id = blockIdx.x;
  int e = ((id & 7) << 1) | ((id >> 3) & 1);
  int rest = id >> 4;          // 0..39
  int dt = rest & 7;           // d-tile (128 d)
  int tt = rest >> 3;          // tok-tile (256 slots), 0..4
  int cnt = min(counts[e * 16], CAP);
  int tb0 = tt * 256;
  if (tb0 >= cnt) return;

  extern __shared__ char smem[];
  int tid = threadIdx.x;
  int wid = tid >> 6, lane = tid & 63, llo = lane & 15, lhi = lane >> 4;
  int dm = wid >> 2, wn = wid & 3;               // wave = d-half(2) x tok-quarter(4)

  f32x4 acc[4][4];                               // per wave: 64 d x 64 tok
#pragma unroll
  for (int i = 0; i < 4; ++i)
#pragma unroll
    for (int j = 0; j < 4; ++j) acc[i][j] = (f32x4){0.f, 0.f, 0.f, 0.f};

  const size_t bbase = ((size_t)e * CAPRG + tt * 16) * 64;   // Ug chunk base (16 rg)

  // per-wave staging pointers; stride per tile: W2s chunks advance 64 chunks
  // (=32768 shorts), Ug chunks advance 1 chunk (=512 shorts)
  const int c0 = wid * 3;
  const unsigned short* gsrc0;
  const unsigned short* gsrc1;
  const unsigned short* gsrc2;
  int st0, st1, st2;
  {
    int c = c0;
    if (c < 8) { gsrc0 = W2s + ((((size_t)e * 64) * 64 + dt * 8 + c) << 9) + lane * 8; st0 = 32768; }
    else       { gsrc0 = Ug + ((bbase + (size_t)(c - 8) * 64) << 9) + lane * 8; st0 = 512; }
    c = c0 + 1;
    if (c < 8) { gsrc1 = W2s + ((((size_t)e * 64) * 64 + dt * 8 + c) << 9) + lane * 8; st1 = 32768; }
    else       { gsrc1 = Ug + ((bbase + (size_t)(c - 8) * 64) << 9) + lane * 8; st1 = 512; }
    c = c0 + 2;
    if (c < 8) { gsrc2 = W2s + ((((size_t)e * 64) * 64 + dt * 8 + c) << 9) + lane * 8; st2 = 32768; }
    else       { gsrc2 = Ug + ((bbase + (size_t)(c - 8) * 64) << 9) + lane * 8; st2 = 512; }
  }
  const int doff0 = (c0 + 0) * 1024;
  const int doff1 = (c0 + 1) * 1024;
  const int doff2 = (c0 + 2) * 1024;
  const int lo16 = lane * 16;
  const int aoff = dm * 4096;
  const int boff = 8192 + wn * 4096;

#define G2_STAGE(ROT)                                                           \
  {                                                                             \
    char* dst = smem + (ROT);                                                   \
    gld_lds16(gsrc0, dst + doff0);                                              \
    gld_lds16(gsrc1, dst + doff1);                                              \
    gld_lds16(gsrc2, dst + doff2);                                              \
    gsrc0 += st0; gsrc1 += st1; gsrc2 += st2;                                   \
  }

  G2_STAGE(0);
  G2_STAGE(24576);
  asm volatile("s_waitcnt vmcnt(3)" ::: "memory");
  __builtin_amdgcn_s_barrier();
  int rotw = 49152, rotr = 0;
  for (int t = 0; t < 64; ++t) {                 // K = 2048, BK = 32
    if (t + 2 < 64) G2_STAGE(rotw);
    const char* bufc = smem + rotr;
    bf16x8 aw[4], bu[4];
#pragma unroll
    for (int di = 0; di < 4; ++di)
      aw[di] = *(const bf16x8*)(bufc + aoff + di * 1024 + lo16);
#pragma unroll
    for (int ti = 0; ti < 4; ++ti)
      bu[ti] = *(const bf16x8*)(bufc + boff + ti * 1024 + lo16);
#pragma unroll
    for (int di = 0; di < 4; ++di)
#pragma unroll
      for (int ti = 0; ti < 4; ++ti)
        acc[di][ti] = __builtin_amdgcn_mfma_f32_16x16x32_bf16(aw[di], bu[ti], acc[di][ti], 0, 0, 0);
    asm volatile("s_waitcnt lgkmcnt(0)" ::: "memory");
    __builtin_amdgcn_sched_barrier(0);
    if (t + 2 < 64) {
      asm volatile("s_waitcnt vmcnt(3)" ::: "memory");
    } else if (t + 1 < 64) {
      asm volatile("s_waitcnt vmcnt(0)" ::: "memory");
    }
    __builtin_amdgcn_s_barrier();
    rotw = (rotw == 49152) ? 0 : rotw + 24576;
    rotr = (rotr == 49152) ? 0 : rotr + 24576;
  }

  // epilogue: plain bf16 partial stores (no RMW, no atomics)
#pragma unroll
  for (int di = 0; di < 4; ++di)
#pragma unroll
    for (int ti = 0; ti < 4; ++ti) {
      int slot = tb0 + wn * 64 + ti * 16 + llo;
      int d = dt * 128 + dm * 64 + di * 16 + 4 * lhi;
      uint2 v;
      v.x = pk2(acc[di][ti][0], acc[di][ti][1]);
      v.y = pk2(acc[di][ti][2], acc[di][ti][3]);
      *(uint2*)(Yp + (((size_t)e * CAP + slot) << 10) + d) = v;
    }
}

// ---------------- combine: out[tok] = w0*Yp[p0] + w1*Yp[p1] (streaming) ----------
__global__ __launch_bounds__(256) void combine_k(
    const unsigned short* __restrict__ Yp, const int* __restrict__ pos,
    const float* __restrict__ tw, float* __restrict__ out) {
  int gid = blockIdx.x * 256 + threadIdx.x;    // 1,048,576 threads
  int tok = gid >> 7, oct = gid & 127;
  int p0 = pos[tok * 2], p1 = pos[tok * 2 + 1];
  float w0 = tw[tok * 2], w1 = tw[tok * 2 + 1];
  float r[8];
#pragma unroll
  for (int j = 0; j < 8; ++j) r[j] = 0.f;
  if (p0 >= 0) {
    uint4 a = *(const uint4*)(Yp + (((size_t)p0) << 10) + (oct << 3));
    unsigned int w[4] = {a.x, a.y, a.z, a.w};
#pragma unroll
    for (int h = 0; h < 4; ++h) {
      r[2 * h]     += w0 * bf2f(w[h] & 0xffffu);
      r[2 * h + 1] += w0 * bf2f(w[h] >> 16);
    }
  }
  if (p1 >= 0) {
    uint4 a = *(const uint4*)(Yp + (((size_t)p1) << 10) + (oct << 3));
    unsigned int w[4] = {a.x, a.y, a.z, a.w};
#pragma unroll
    for (int h = 0; h < 4; ++h) {
      r[2 * h]     += w1 * bf2f(w[h] & 0xffffu);
      r[2 * h + 1] += w1 * bf2f(w[h] >> 16);
    }
  }
  float4 o0 = {r[0], r[1], r[2], r[3]}, o1 = {r[4], r[5], r[6], r[7]};
  float* dst = out + ((size_t)tok << 10) + (oct << 3);
  *(float4*)dst = o0;
  *(float4*)(dst + 4) = o1;
}

extern "C" void kernel_launch(void* const* d_in, const int* in_sizes, int n_in,
                              void* d_out, int out_size, void* d_ws, size_t ws_size,
                              hipStream_t stream) {
  const float* x  = (const float*)d_in[0];
  const float* Wg = (const float*)d_in[1];
  const float* W1 = (const float*)d_in[2];
  const float* W2 = (const float*)d_in[3];
  float* out = (float*)d_out;

  int*   counts = (int*)((char*)d_ws + WS_COUNTS);   // padded: counts[e*16]
  int*   tokl   = (int*)((char*)d_ws + WS_TOKL);
  float* wgtl   = (float*)((char*)d_ws + WS_WGTL);
  int*   pos    = (int*)((char*)d_ws + WS_POS);
  float* tw     = (float*)((char*)d_ws + WS_TW);
  unsigned short* XgN = (unsigned short*)((char*)d_ws + WS2_XG);  // Xg, then Yp
  unsigned short* W1n = (unsigned short*)((char*)d_ws + WS2_W1);
  unsigned short* W2n = (unsigned short*)((char*)d_ws + WS2_W2);
  unsigned short* UgN = (unsigned short*)((char*)d_ws + WS2_UG);

  hipMemsetAsync(counts, 0, 1024, stream);

  gate_kernel<<<NTOK / 16, 1024, 0, stream>>>(x, Wg, counts, tokl, wgtl, pos, tw);
  convert_w2<<<16384, 256, 0, stream>>>(W1, W2, W1n, W2n);
  gather_x<<<5120, 512, 0, stream>>>(x, counts, tokl, XgN);

  hipFuncSetAttribute((const void*)g1,
                      hipFuncAttributeMaxDynamicSharedMemorySize, 73728);
  hipFuncSetAttribute((const void*)g2,
                      hipFuncAttributeMaxDynamicSharedMemorySize, 73728);
  g1<<<NEXP * 16 * 5, 512, 73728, stream>>>(W1n, XgN, counts, UgN);
  g2<<<NEXP * 8 * 5, 512, 73728, stream>>>(W2n, UgN, counts, XgN /* = Yp */);
  combine_k<<<4096, 256, 0, stream>>>(XgN /* = Yp */, pos, tw, out);
}

// Round 20
// 341.762 us; speedup vs baseline: 1.0464x; 1.0018x over previous
//
#include <hip/hip_runtime.h>
#include <hip/hip_bf16.h>

#define NTOK 8192   // B*T tokens
#define DDIM 1024
#define FDIM 2048
#define NEXP 16
#define CAP   1280  // max token slots per expert (cnt ~1024 expected)
#define CAPRG 80    // CAP/16 row-groups

// ---------------- workspace layout (bytes) ----------------
#define WS_COUNTS 0                                  // int[16*16], 64B-padded per expert
#define WS_TOKL   4096
#define WS_WGTL   (4096 + NTOK*NEXP*4)
#define WS_POS    (4096 + 2*NTOK*NEXP*4)            // int[NTOK*2]
#define WS_TW     (4096 + 2*NTOK*NEXP*4 + NTOK*8)   // float[NTOK*2]
#define WS2_XG   (size_t)(2u<<20)     // 40 MB: Xg (g1 input), then reused as Yp (g2 out)
#define WS2_W1   (size_t)(42u<<20)    // 64 MB: 16*128*32 chunks  (std frag order)
#define WS2_W2   (size_t)(106u<<20)   // 64 MB: 16*64*64 chunks   (SIGMA frag order)
#define WS2_UG   (size_t)(170u<<20)   // 80 MB: 16*80*64 chunks   (SIGMA frag order)

typedef short bf16x8 __attribute__((ext_vector_type(8)));
typedef float f32x4  __attribute__((ext_vector_type(4)));

__device__ __forceinline__ unsigned short f2bf(float f) {
  unsigned int u = __builtin_bit_cast(unsigned int, f);
  u += 0x7fffu + ((u >> 16) & 1u);            // RNE
  return (unsigned short)(u >> 16);
}
__device__ __forceinline__ unsigned int pk2(float a, float b) {
  return (unsigned int)f2bf(a) | ((unsigned int)f2bf(b) << 16);
}
__device__ __forceinline__ float bf2f(unsigned int u) {
  return __builtin_bit_cast(float, u << 16);
}
__device__ __forceinline__ float silu_f(float s) {
  return s / (1.f + __expf(-s));
}
__device__ __forceinline__ void gld_lds16(const void* g, void* l) {
  __builtin_amdgcn_global_load_lds((const __attribute__((address_space(1))) void*)g,
                                   (__attribute__((address_space(3))) void*)l, 16, 0, 0);
}

// ---------------- gate v3: block-aggregated slot allocation, padded counters ----------
__global__ __launch_bounds__(1024) void gate_kernel(
    const float* __restrict__ x, const float* __restrict__ Wg,
    int* __restrict__ counts, int* __restrict__ tokl, float* __restrict__ wgtl,
    int* __restrict__ pos, float* __restrict__ tw) {
  __shared__ float WgT[NEXP][DDIM];            // 64 KB
  __shared__ int   se[32];
  __shared__ float swt[32];
  __shared__ int   sbase[16];
  int tid = threadIdx.x;
#pragma unroll
  for (int i = 0; i < 4; ++i) {
    int i4 = i * 1024 + tid;
    float4 v = ((const float4*)Wg)[i4];
    int k = i4 >> 2;
    int e0 = (i4 * 4) & 15;
    WgT[e0][k] = v.x; WgT[e0 + 1][k] = v.y;
    WgT[e0 + 2][k] = v.z; WgT[e0 + 3][k] = v.w;
  }
  __syncthreads();

  int wid = tid >> 6, lane = tid & 63;
  int tok = blockIdx.x * 16 + wid;
  const float* xr = x + (size_t)tok * DDIM;
  float xv[16];
#pragma unroll
  for (int j = 0; j < 16; ++j) xv[j] = xr[lane + 64 * j];
  float lg[NEXP];
#pragma unroll
  for (int e = 0; e < NEXP; ++e) {
    float s = 0.f;
#pragma unroll
    for (int j = 0; j < 16; ++j) s += xv[j] * WgT[e][lane + 64 * j];
#pragma unroll
    for (int off = 32; off > 0; off >>= 1) s += __shfl_xor(s, off);
    lg[e] = s;
  }
  int e0 = 0; float b0 = lg[0];
#pragma unroll
  for (int e = 1; e < NEXP; ++e) if (lg[e] > b0) { b0 = lg[e]; e0 = e; }
  int e1 = -1; float b1 = -3.4e38f;
#pragma unroll
  for (int e = 0; e < NEXP; ++e) if (e != e0 && lg[e] > b1) { b1 = lg[e]; e1 = e; }
  float t = expf(b1 - b0);
  float w0 = 1.f / (1.f + t);
  float w1 = t / (1.f + t);
  if (lane == 0) {
    se[wid * 2] = e0;  swt[wid * 2] = w0;
    se[wid * 2 + 1] = e1;  swt[wid * 2 + 1] = w1;
  }
  __syncthreads();

  if (tid < 16) {
    int cnt = 0;
#pragma unroll
    for (int i = 0; i < 32; ++i) cnt += (se[i] == tid) ? 1 : 0;
    sbase[tid] = cnt ? atomicAdd(&counts[tid * 16], cnt) : 0;
    int slot = sbase[tid];
    for (int i = 0; i < 32; ++i) {
      if (se[i] == tid) {
        int tk = blockIdx.x * 16 + (i >> 1);
        float w = swt[i];
        if (slot < CAP) { tokl[tid * NTOK + slot] = tk; wgtl[tid * NTOK + slot] = w; }
        pos[tk * 2 + (i & 1)] = (slot < CAP) ? (tid * CAP + slot) : -1;
        tw[tk * 2 + (i & 1)] = w;
        slot++;
      }
    }
  }
}

// ---------------- W fp32 -> bf16 frag-ordered, LDS-transposed (coalesced reads) ----
__global__ __launch_bounds__(256) void convert_w2(
    const float* __restrict__ W1, const float* __restrict__ W2,
    unsigned short* __restrict__ W1s, unsigned short* __restrict__ W2s) {
  __shared__ float tile[32][133];
  int b = blockIdx.x;
  bool isw2 = b >= 8192;
  int bb = isw2 ? b - 8192 : b;
  int e = bb >> 9;
  int r = bb & 511;
  int t = threadIdx.x;
  const float* src;
  int kk, cb, C;
  if (!isw2) {
    kk = r >> 4; cb = r & 15; C = FDIM;
    src = W1 + ((size_t)e << 21) + (size_t)(kk * 32) * FDIM + cb * 128;
  } else {
    kk = r >> 3; cb = r & 7; C = DDIM;
    src = W2 + ((size_t)e << 21) + (size_t)(kk * 32) * DDIM + cb * 128;
  }
  int c4 = (t & 31) * 4, rr0 = t >> 5;
#pragma unroll
  for (int rd = 0; rd < 4; ++rd) {
    int rr = rr0 + rd * 8;
    float4 v = *(const float4*)(src + (size_t)rr * C + c4);
    tile[rr][c4] = v.x; tile[rr][c4 + 1] = v.y;
    tile[rr][c4 + 2] = v.z; tile[rr][c4 + 3] = v.w;
  }
  __syncthreads();
  int w = t >> 6, lane = t & 63, llo = lane & 15, lhi = lane >> 4;
#pragma unroll
  for (int u = 0; u < 2; ++u) {
    int c2 = w * 2 + u;
    float v[8];
#pragma unroll
    for (int j = 0; j < 8; ++j) {
      int row = isw2 ? (4 * lhi + (j & 3) + 16 * (j >> 2)) : (lhi * 8 + j);
      v[j] = tile[row][c2 * 16 + llo];
    }
    uint4 o;
    o.x = pk2(v[0], v[1]); o.y = pk2(v[2], v[3]);
    o.z = pk2(v[4], v[5]); o.w = pk2(v[6], v[7]);
    size_t gid = isw2 ? (((size_t)e * 64 + kk) * 64 + (cb * 8 + c2))
                      : (((size_t)e * 128 + (cb * 8 + c2)) * 32 + kk);
    *(uint4*)((isw2 ? W2s : W1s) + (gid << 9) + lane * 8) = o;
  }
}

// ---------------- gather x -> Xg frag-ordered bf16, zero-padded slots ----------------
__global__ __launch_bounds__(512) void gather_x(
    const float* __restrict__ x, const int* __restrict__ counts,
    const int* __restrict__ tokl, unsigned short* __restrict__ Xg) {
  int chunk = blockIdx.x * 8 + (threadIdx.x >> 6);   // 40960 chunks
  int lane = threadIdx.x & 63, llo = lane & 15, lhi = lane >> 4;
  int kb = chunk & 31;
  int rg = (chunk >> 5) % CAPRG;
  int e = chunk / (CAPRG * 32);
  int cnt = min(counts[e * 16], CAP);
  int slot = rg * 16 + llo;
  uint4 o = {0u, 0u, 0u, 0u};
  if (slot < cnt) {
    int tok = tokl[e * NTOK + slot];
    const float* p = x + (size_t)tok * DDIM + kb * 32 + lhi * 8;
    float4 a = *(const float4*)p, b2 = *(const float4*)(p + 4);
    o.x = pk2(a.x, a.y); o.y = pk2(a.z, a.w);
    o.z = pk2(b2.x, b2.y); o.w = pk2(b2.z, b2.w);
  }
  *(uint4*)(Xg + ((size_t)chunk << 9) + lane * 8) = o;
}

// ======== G1: U = silu(X @ W1e), 128f x 256tok, BK=32, 3-buffer depth-2 pipeline ====
// R20 = R17 + T5: s_setprio(1) around the MFMA cluster (role-split across the 2
// co-resident blocks -> scheduler prefers MFMA-entering waves over staging waves).
__global__ __launch_bounds__(512, 4) void g1(
    const unsigned short* __restrict__ W1s, const unsigned short* __restrict__ Xg,
    const int* __restrict__ counts, unsigned short* __restrict__ Ug) {
  int id = blockIdx.x;
  int e = ((id & 7) << 1) | ((id >> 3) & 1);
  int rest = id >> 4;          // 0..79
  int ft = rest & 15;          // f-tile (128 f)
  int tt = rest >> 4;          // tok-tile (256 slots), 0..4
  int cnt = min(counts[e * 16], CAP);
  if (tt * 256 >= cnt) return;

  extern __shared__ char smem[];                 // 3 x (A 8KB | B 16KB)
  int tid = threadIdx.x, wid = tid >> 6, lane = tid & 63;
  int llo = lane & 15, lhi = lane >> 4;
  int fm = wid >> 2, wn = wid & 3;               // wave = f-half(2) x tok-quarter(4)

  f32x4 acc[4][4];                               // per wave: 64 f x 64 tok
#pragma unroll
  for (int i = 0; i < 4; ++i)
#pragma unroll
    for (int j = 0; j < 4; ++j) acc[i][j] = (f32x4){0.f, 0.f, 0.f, 0.f};

  const size_t abase = ((size_t)e * 128 + ft * 8) * 32;      // W1s chunk base (8 ff)
  const size_t bbase = ((size_t)e * CAPRG + tt * 16) * 32;   // Xg chunk base (16 rg)

  // per-wave staging pointers (3 chunks), stride 512 shorts (1 chunk) per tile
  const int c0 = wid * 3;
  const unsigned short* gsrc0;
  const unsigned short* gsrc1;
  const unsigned short* gsrc2;
  {
    int c = c0;
    gsrc0 = (c < 8) ? W1s + ((abase + (size_t)c * 32) << 9) + lane * 8
                    : Xg + ((bbase + (size_t)(c - 8) * 32) << 9) + lane * 8;
    c = c0 + 1;
    gsrc1 = (c < 8) ? W1s + ((abase + (size_t)c * 32) << 9) + lane * 8
                    : Xg + ((bbase + (size_t)(c - 8) * 32) << 9) + lane * 8;
    c = c0 + 2;
    gsrc2 = (c < 8) ? W1s + ((abase + (size_t)c * 32) << 9) + lane * 8
                    : Xg + ((bbase + (size_t)(c - 8) * 32) << 9) + lane * 8;
  }
  const int doff0 = (c0 + 0) * 1024;
  const int doff1 = (c0 + 1) * 1024;
  const int doff2 = (c0 + 2) * 1024;
  const int lo16 = lane * 16;
  const int aoff = fm * 4096;                    // af region base
  const int boff = 8192 + wn * 4096;             // bx region base

#define G1_STAGE(ROT)                                                           \
  {                                                                             \
    char* dst = smem + (ROT);                                                   \
    gld_lds16(gsrc0, dst + doff0);                                              \
    gld_lds16(gsrc1, dst + doff1);                                              \
    gld_lds16(gsrc2, dst + doff2);                                              \
    gsrc0 += 512; gsrc1 += 512; gsrc2 += 512;                                   \
  }

  G1_STAGE(0);
  G1_STAGE(24576);
  asm volatile("s_waitcnt vmcnt(3)" ::: "memory");
  __builtin_amdgcn_s_barrier();
  int rotw = 49152, rotr = 0;
  for (int t = 0; t < 32; ++t) {                 // K = 1024, BK = 32
    if (t + 2 < 32) G1_STAGE(rotw);
    const char* bufc = smem + rotr;
    bf16x8 af[4], bx[4];
#pragma unroll
    for (int fi = 0; fi < 4; ++fi)
      af[fi] = *(const bf16x8*)(bufc + aoff + fi * 1024 + lo16);
#pragma unroll
    for (int ti = 0; ti < 4; ++ti)
      bx[ti] = *(const bf16x8*)(bufc + boff + ti * 1024 + lo16);
    __builtin_amdgcn_s_setprio(1);
#pragma unroll
    for (int fi = 0; fi < 4; ++fi)
#pragma unroll
      for (int ti = 0; ti < 4; ++ti)
        acc[fi][ti] = __builtin_amdgcn_mfma_f32_16x16x32_bf16(af[fi], bx[ti], acc[fi][ti], 0, 0, 0);
    __builtin_amdgcn_s_setprio(0);
    // drain this wave's LDS reads before any wave can overwrite this buffer
    asm volatile("s_waitcnt lgkmcnt(0)" ::: "memory");
    __builtin_amdgcn_sched_barrier(0);
    if (t + 2 < 32) {
      asm volatile("s_waitcnt vmcnt(3)" ::: "memory");   // retire tile t+1; t+2 in flight
    } else if (t + 1 < 32) {
      asm volatile("s_waitcnt vmcnt(0)" ::: "memory");   // tail: drain t+1
    }
    __builtin_amdgcn_s_barrier();
    rotw = (rotw == 49152) ? 0 : rotw + 24576;
    rotr = (rotr == 49152) ? 0 : rotr + 24576;
  }

  // epilogue: silu -> Ug (SIGMA order), coalesced 16B stores straight from regs
#pragma unroll
  for (int ti = 0; ti < 4; ++ti) {
    int rg = tt * 16 + wn * 4 + ti;
#pragma unroll
    for (int p = 0; p < 2; ++p) {
      int fo = ft * 4 + fm * 2 + p;
      uint4 v;
      v.x = pk2(silu_f(acc[2 * p][ti][0]), silu_f(acc[2 * p][ti][1]));
      v.y = pk2(silu_f(acc[2 * p][ti][2]), silu_f(acc[2 * p][ti][3]));
      v.z = pk2(silu_f(acc[2 * p + 1][ti][0]), silu_f(acc[2 * p + 1][ti][1]));
      v.w = pk2(silu_f(acc[2 * p + 1][ti][2]), silu_f(acc[2 * p + 1][ti][3]));
      *(uint4*)(Ug + ((((size_t)e * CAPRG + rg) * 64 + fo) << 9) + lane * 8) = v;
    }
  }
}

// ======== G2: Yp = U @ W2e, 128d x 256tok, BK=32, 3-buffer depth-2 pipeline ========
__global__ __launch_bounds__(512, 4) void g2(
    const unsigned short* __restrict__ W2s, const unsigned short* __restrict__ Ug,
    const int* __restrict__ counts, unsigned short* __restrict__ Yp) {
  int id = blockIdx.x;
  int e = ((id & 7) << 1) | ((id >> 3) & 1);
  int rest = id >> 4;          // 0..39
  int dt = rest & 7;           // d-tile (128 d)
  int tt = rest >> 3;          // tok-tile (256 slots), 0..4
  int cnt = min(counts[e * 16], CAP);
  int tb0 = tt * 256;
  if (tb0 >= cnt) return;

  extern __shared__ char smem[];
  int tid = threadIdx.x;
  int wid = tid >> 6, lane = tid & 63, llo = lane & 15, lhi = lane >> 4;
  int dm = wid >> 2, wn = wid & 3;               // wave = d-half(2) x tok-quarter(4)

  f32x4 acc[4][4];                               // per wave: 64 d x 64 tok
#pragma unroll
  for (int i = 0; i < 4; ++i)
#pragma unroll
    for (int j = 0; j < 4; ++j) acc[i][j] = (f32x4){0.f, 0.f, 0.f, 0.f};

  const size_t bbase = ((size_t)e * CAPRG + tt * 16) * 64;   // Ug chunk base (16 rg)

  // per-wave staging pointers; stride per tile: W2s chunks advance 64 chunks
  // (=32768 shorts), Ug chunks advance 1 chunk (=512 shorts)
  const int c0 = wid * 3;
  const unsigned short* gsrc0;
  const unsigned short* gsrc1;
  const unsigned short* gsrc2;
  int st0, st1, st2;
  {
    int c = c0;
    if (c < 8) { gsrc0 = W2s + ((((size_t)e * 64) * 64 + dt * 8 + c) << 9) + lane * 8; st0 = 32768; }
    else       { gsrc0 = Ug + ((bbase + (size_t)(c - 8) * 64) << 9) + lane * 8; st0 = 512; }
    c = c0 + 1;
    if (c < 8) { gsrc1 = W2s + ((((size_t)e * 64) * 64 + dt * 8 + c) << 9) + lane * 8; st1 = 32768; }
    else       { gsrc1 = Ug + ((bbase + (size_t)(c - 8) * 64) << 9) + lane * 8; st1 = 512; }
    c = c0 + 2;
    if (c < 8) { gsrc2 = W2s + ((((size_t)e * 64) * 64 + dt * 8 + c) << 9) + lane * 8; st2 = 32768; }
    else       { gsrc2 = Ug + ((bbase + (size_t)(c - 8) * 64) << 9) + lane * 8; st2 = 512; }
  }
  const int doff0 = (c0 + 0) * 1024;
  const int doff1 = (c0 + 1) * 1024;
  const int doff2 = (c0 + 2) * 1024;
  const int lo16 = lane * 16;
  const int aoff = dm * 4096;
  const int boff = 8192 + wn * 4096;

#define G2_STAGE(ROT)                                                           \
  {                                                                             \
    char* dst = smem + (ROT);                                                   \
    gld_lds16(gsrc0, dst + doff0);                                              \
    gld_lds16(gsrc1, dst + doff1);                                              \
    gld_lds16(gsrc2, dst + doff2);                                              \
    gsrc0 += st0; gsrc1 += st1; gsrc2 += st2;                                   \
  }

  G2_STAGE(0);
  G2_STAGE(24576);
  asm volatile("s_waitcnt vmcnt(3)" ::: "memory");
  __builtin_amdgcn_s_barrier();
  int rotw = 49152, rotr = 0;
  for (int t = 0; t < 64; ++t) {                 // K = 2048, BK = 32
    if (t + 2 < 64) G2_STAGE(rotw);
    const char* bufc = smem + rotr;
    bf16x8 aw[4], bu[4];
#pragma unroll
    for (int di = 0; di < 4; ++di)
      aw[di] = *(const bf16x8*)(bufc + aoff + di * 1024 + lo16);
#pragma unroll
    for (int ti = 0; ti < 4; ++ti)
      bu[ti] = *(const bf16x8*)(bufc + boff + ti * 1024 + lo16);
    __builtin_amdgcn_s_setprio(1);
#pragma unroll
    for (int di = 0; di < 4; ++di)
#pragma unroll
      for (int ti = 0; ti < 4; ++ti)
        acc[di][ti] = __builtin_amdgcn_mfma_f32_16x16x32_bf16(aw[di], bu[ti], acc[di][ti], 0, 0, 0);
    __builtin_amdgcn_s_setprio(0);
    asm volatile("s_waitcnt lgkmcnt(0)" ::: "memory");
    __builtin_amdgcn_sched_barrier(0);
    if (t + 2 < 64) {
      asm volatile("s_waitcnt vmcnt(3)" ::: "memory");
    } else if (t + 1 < 64) {
      asm volatile("s_waitcnt vmcnt(0)" ::: "memory");
    }
    __builtin_amdgcn_s_barrier();
    rotw = (rotw == 49152) ? 0 : rotw + 24576;
    rotr = (rotr == 49152) ? 0 : rotr + 24576;
  }

  // epilogue: plain bf16 partial stores (no RMW, no atomics)
#pragma unroll
  for (int di = 0; di < 4; ++di)
#pragma unroll
    for (int ti = 0; ti < 4; ++ti) {
      int slot = tb0 + wn * 64 + ti * 16 + llo;
      int d = dt * 128 + dm * 64 + di * 16 + 4 * lhi;
      uint2 v;
      v.x = pk2(acc[di][ti][0], acc[di][ti][1]);
      v.y = pk2(acc[di][ti][2], acc[di][ti][3]);
      *(uint2*)(Yp + (((size_t)e * CAP + slot) << 10) + d) = v;
    }
}

// ---------------- combine: out[tok] = w0*Yp[p0] + w1*Yp[p1] (streaming) ----------
__global__ __launch_bounds__(256) void combine_k(
    const unsigned short* __restrict__ Yp, const int* __restrict__ pos,
    const float* __restrict__ tw, float* __restrict__ out) {
  int gid = blockIdx.x * 256 + threadIdx.x;    // 1,048,576 threads
  int tok = gid >> 7, oct = gid & 127;
  int p0 = pos[tok * 2], p1 = pos[tok * 2 + 1];
  float w0 = tw[tok * 2], w1 = tw[tok * 2 + 1];
  float r[8];
#pragma unroll
  for (int j = 0; j < 8; ++j) r[j] = 0.f;
  if (p0 >= 0) {
    uint4 a = *(const uint4*)(Yp + (((size_t)p0) << 10) + (oct << 3));
    unsigned int w[4] = {a.x, a.y, a.z, a.w};
#pragma unroll
    for (int h = 0; h < 4; ++h) {
      r[2 * h]     += w0 * bf2f(w[h] & 0xffffu);
      r[2 * h + 1] += w0 * bf2f(w[h] >> 16);
    }
  }
  if (p1 >= 0) {
    uint4 a = *(const uint4*)(Yp + (((size_t)p1) << 10) + (oct << 3));
    unsigned int w[4] = {a.x, a.y, a.z, a.w};
#pragma unroll
    for (int h = 0; h < 4; ++h) {
      r[2 * h]     += w1 * bf2f(w[h] & 0xffffu);
      r[2 * h + 1] += w1 * bf2f(w[h] >> 16);
    }
  }
  float4 o0 = {r[0], r[1], r[2], r[3]}, o1 = {r[4], r[5], r[6], r[7]};
  float* dst = out + ((size_t)tok << 10) + (oct << 3);
  *(float4*)dst = o0;
  *(float4*)(dst + 4) = o1;
}

extern "C" void kernel_launch(void* const* d_in, const int* in_sizes, int n_in,
                              void* d_out, int out_size, void* d_ws, size_t ws_size,
                              hipStream_t stream) {
  const float* x  = (const float*)d_in[0];
  const float* Wg = (const float*)d_in[1];
  const float* W1 = (const float*)d_in[2];
  const float* W2 = (const float*)d_in[3];
  float* out = (float*)d_out;

  int*   counts = (int*)((char*)d_ws + WS_COUNTS);   // padded: counts[e*16]
  int*   tokl   = (int*)((char*)d_ws + WS_TOKL);
  float* wgtl   = (float*)((char*)d_ws + WS_WGTL);
  int*   pos    = (int*)((char*)d_ws + WS_POS);
  float* tw     = (float*)((char*)d_ws + WS_TW);
  unsigned short* XgN = (unsigned short*)((char*)d_ws + WS2_XG);  // Xg, then Yp
  unsigned short* W1n = (unsigned short*)((char*)d_ws + WS2_W1);
  unsigned short* W2n = (unsigned short*)((char*)d_ws + WS2_W2);
  unsigned short* UgN = (unsigned short*)((char*)d_ws + WS2_UG);

  hipMemsetAsync(counts, 0, 1024, stream);

  gate_kernel<<<NTOK / 16, 1024, 0, stream>>>(x, Wg, counts, tokl, wgtl, pos, tw);
  convert_w2<<<16384, 256, 0, stream>>>(W1, W2, W1n, W2n);
  gather_x<<<5120, 512, 0, stream>>>(x, counts, tokl, XgN);

  hipFuncSetAttribute((const void*)g1,
                      hipFuncAttributeMaxDynamicSharedMemorySize, 73728);
  hipFuncSetAttribute((const void*)g2,
                      hipFuncAttributeMaxDynamicSharedMemorySize, 73728);
  g1<<<NEXP * 16 * 5, 512, 73728, stream>>>(W1n, XgN, counts, UgN);
  g2<<<NEXP * 8 * 5, 512, 73728, stream>>>(W2n, UgN, counts, XgN /* = Yp */);
  combine_k<<<4096, 256, 0, stream>>>(XgN /* = Yp */, pos, tw, out);
}